// Round 4
// baseline (13634.715 us; speedup 1.0000x reference)
//
#include <hip/hip_runtime.h>

// ---------- problem constants ----------
// V=50000, E=300, H=512, BS=64, NSEG=3, SLEN=256 -> B3=192
// NNODE=18, NFEAT=600, NHID=600, NOUT=1024
// ALL float inputs/outputs are fp32 (reference is jnp.float32).

typedef unsigned short ushort_t;
typedef __attribute__((ext_vector_type(8))) short bf16x8;   // 8 bf16 = 4 VGPRs
typedef __attribute__((ext_vector_type(4))) float f32x4;

// output element offsets (fp32 elements)
#define OUT_RFTS 0UL
#define OUT_EMBS 25165824UL          // 64*768*512
#define OUT_MSKS 39911424UL          // + 64*768*300
#define OUT_SG   39960576UL          // + 64*768
#define OUT_HIDS 41140224UL          // + 64*18*1024   (end 41238528 = out_size)

// workspace byte offsets (total ~3.2 MB)
#define WS_HX   0UL                  // hx: 2*192*512 bf16 = 393,216 B (internal)
#define WS_CTR  393216UL             // ctr: 12*8B (padded to 256)
#define WS_H1   393472UL             // h1: 64*18*600 fp32 = 2,764,800 B

__device__ __forceinline__ ushort_t f2b(float f) {
  unsigned int u = __float_as_uint(f);
  u += 0x7fffu + ((u >> 16) & 1u);          // RNE
  return (ushort_t)(u >> 16);
}
__device__ __forceinline__ float b2f(ushort_t x) {
  return __uint_as_float(((unsigned int)x) << 16);
}

union FRAG { ushort_t s[8]; bf16x8 v; uint2 u2[2]; };

// build a bf16x8 fragment from 8 fp32 (16B-aligned), with per-half validity
__device__ __forceinline__ bf16x8 frag_from_f32(const float* p, bool v0, bool v1) {
  float4 a = v0 ? *(const float4*)p       : make_float4(0.f, 0.f, 0.f, 0.f);
  float4 b = v1 ? *(const float4*)(p + 4) : make_float4(0.f, 0.f, 0.f, 0.f);
  FRAG u;
  u.s[0] = f2b(a.x); u.s[1] = f2b(a.y); u.s[2] = f2b(a.z); u.s[3] = f2b(a.w);
  u.s[4] = f2b(b.x); u.s[5] = f2b(b.y); u.s[6] = f2b(b.z); u.s[7] = f2b(b.w);
  return u.v;
}

// =====================================================================
// Fused GRU: gather + input projection + recurrence in one persistent
// kernel. 12 groups (16 samples) x 8 gate-slices = 96 WGs, 1 WG/CU.
// Weights register-resident as bf16 frags (converted from fp32 once).
// Per-step h exchange via agent-scope double-buffered bf16 hx +
// monotonic per-group counter barrier. tok prefetched 1 step ahead.
// =====================================================================
__global__ __launch_bounds__(256, 1) void gru_fused(
    const int* __restrict__ inds, const int* __restrict__ lens,
    const float* __restrict__ emb, const float* __restrict__ w_ih,
    const float* __restrict__ w_hh, const float* __restrict__ b_ih,
    const float* __restrict__ b_hh, ushort_t* __restrict__ hx,
    unsigned long long* __restrict__ ctr, float* __restrict__ out)
{
  const int g = blockIdx.x >> 3;        // group 0..11
  const int p = blockIdx.x & 7;         // gate-slice 0..7 (64 j each)
  const int tid = threadIdx.x;
  const int w = tid >> 6;               // wave 0..3, owns j-subtile w
  const int l = tid & 63;
  const int jc = l & 15;
  const int quad = l >> 4;
  const int jg = p * 64 + w * 16 + jc;  // j in [0,512)

  __shared__ ushort_t hst[16 * 520];    // staged h (16 x 512 bf16, stride 520)
  __shared__ ushort_t tokb[2][16 * 328];// staged tok (16 x 320 bf16, stride 328)
  __shared__ int sidx[16];              // emb row indices for next step

  // ---- register-resident w_hh slice: B[n=l&15][k=quad*8+i] frags ----
  bf16x8 bwh[3][16];
#pragma unroll
  for (int g3 = 0; g3 < 3; ++g3) {
    const float* wr = w_hh + (size_t)(g3 * 512 + jg) * 512 + quad * 8;
#pragma unroll
    for (int kc = 0; kc < 16; ++kc)
      bwh[g3][kc] = frag_from_f32(wr + kc * 32, true, true);
  }
  // ---- register-resident w_ih slice (K=300 padded to 320 with zeros) ----
  bf16x8 bwx[3][10];
#pragma unroll
  for (int g3 = 0; g3 < 3; ++g3) {
    const float* wr = w_ih + (size_t)(g3 * 512 + jg) * 300;
#pragma unroll
    for (int kc = 0; kc < 10; ++kc) {
      const int k0 = kc * 32 + quad * 8;
      bwx[g3][kc] = frag_from_f32(wr + k0, k0 + 3 < 300, k0 + 7 < 300);
    }
  }
  const float bsr = b_ih[jg] + b_hh[jg];
  const float bsz = b_ih[512 + jg] + b_hh[512 + jg];
  const float bin = b_ih[1024 + jg];
  const float bhn = b_hh[1024 + jg];

  int Tg = 0;
  for (int i = 0; i < 16; ++i) Tg = max(Tg, lens[g * 16 + i]);

  int len_q[4]; size_t rf_q[4], hxo_q[4], hid_q[4];
  float h_q[4] = {0.f, 0.f, 0.f, 0.f};
#pragma unroll
  for (int q = 0; q < 4; ++q) {
    int sl = quad * 4 + q;              // sample-in-group (D-row layout)
    int b3 = g * 16 + sl;
    len_q[q] = lens[b3];
    int b = b3 / 3, seg = b3 - b * 3;
    int off = 0;
    for (int ss = 0; ss < seg; ++ss) off += lens[b * 3 + ss];
    rf_q[q]  = OUT_RFTS + ((size_t)b * 768 + off) * 512 + jg;
    hxo_q[q] = (size_t)b3 * 512 + (size_t)(jg & ~1);
    hid_q[q] = OUT_HIDS + (size_t)b3 * 512 + jg;
  }

  // per-thread constant mapping for tok staging: 1280 slots = 16 rows x 80 f4
  int trow[5], tcu[5];
#pragma unroll
  for (int c = 0; c < 5; ++c) {
    int u = c * 256 + tid;
    trow[c] = u / 80;
    tcu[c]  = u - trow[c] * 80;
  }

  // ---- prologue: stage tok for t=0 into tokb[0] ----
  if (tid < 16) sidx[tid] = inds[(size_t)(g * 16 + tid) * 256 + 0];
  __syncthreads();
#pragma unroll
  for (int c = 0; c < 5; ++c) {
    float4 v = make_float4(0.f, 0.f, 0.f, 0.f);
    if (tcu[c] < 75)
      v = *(const float4*)(emb + (size_t)sidx[trow[c]] * 300 + tcu[c] * 4);
    FRAG u; u.s[0] = f2b(v.x); u.s[1] = f2b(v.y); u.s[2] = f2b(v.z); u.s[3] = f2b(v.w);
    *(uint2*)(&tokb[0][trow[c] * 328 + tcu[c] * 4]) = u.u2[0];
  }
  __syncthreads();

  const int HXE = 192 * 512;            // bf16 elements per hx buffer
  const f32x4 z4 = {0.f, 0.f, 0.f, 0.f};

  for (int t = 0; t < Tg; ++t) {
    const int buf = t & 1, nbuf = buf ^ 1;
    // ---- next step's emb indices + stage h (agent-acquire) ----
    if (tid < 16) {
      int tt = (t + 1 < 256) ? t + 1 : 255;
      sidx[tid] = inds[(size_t)(g * 16 + tid) * 256 + tt];
    }
    {
      const unsigned long long* src =
          (const unsigned long long*)(hx + (size_t)buf * HXE + (size_t)g * 16 * 512);
#pragma unroll
      for (int c = 0; c < 8; ++c) {
        int idx = c * 256 + tid;        // 0..2047 (8B units), 128/row
        unsigned long long v = __hip_atomic_load(
            (unsigned long long*)(src + idx), __ATOMIC_ACQUIRE, __HIP_MEMORY_SCOPE_AGENT);
        int row = idx >> 7, col = idx & 127;
        *(unsigned long long*)(&hst[row * 520 + col * 4]) = v;
      }
    }
    __syncthreads();
    // ---- prefetch tok for t+1 (fp32; converted at commit time) ----
    float4 tr[5];
#pragma unroll
    for (int c = 0; c < 5; ++c) {
      tr[c] = make_float4(0.f, 0.f, 0.f, 0.f);
      if (tcu[c] < 75)
        tr[c] = *(const float4*)(emb + (size_t)sidx[trow[c]] * 300 + tcu[c] * 4);
    }
    // ---- MFMA phase: gates = h @ w_hh^T + x @ w_ih^T ----
    f32x4 accr = z4, accz = z4, anh = z4, anx = z4;
#pragma unroll
    for (int kc = 0; kc < 16; ++kc) {
      bf16x8 af = *(const bf16x8*)(&hst[(l & 15) * 520 + kc * 32 + quad * 8]);
      accr = __builtin_amdgcn_mfma_f32_16x16x32_bf16(af, bwh[0][kc], accr, 0, 0, 0);
      accz = __builtin_amdgcn_mfma_f32_16x16x32_bf16(af, bwh[1][kc], accz, 0, 0, 0);
      anh  = __builtin_amdgcn_mfma_f32_16x16x32_bf16(af, bwh[2][kc], anh, 0, 0, 0);
    }
#pragma unroll
    for (int kc = 0; kc < 10; ++kc) {
      bf16x8 xf = *(const bf16x8*)(&tokb[buf][(l & 15) * 328 + kc * 32 + quad * 8]);
      accr = __builtin_amdgcn_mfma_f32_16x16x32_bf16(xf, bwx[0][kc], accr, 0, 0, 0);
      accz = __builtin_amdgcn_mfma_f32_16x16x32_bf16(xf, bwx[1][kc], accz, 0, 0, 0);
      anx  = __builtin_amdgcn_mfma_f32_16x16x32_bf16(xf, bwx[2][kc], anx, 0, 0, 0);
    }
    // ---- gate math + stores ----
    ushort_t* hxout = hx + (size_t)nbuf * HXE;
#pragma unroll
    for (int q = 0; q < 4; ++q) {
      float pr = accr[q] + bsr;
      float pz = accz[q] + bsz;
      float r = 1.f / (1.f + __expf(-pr));
      float z = 1.f / (1.f + __expf(-pz));
      float e2 = __expf(2.f * (anx[q] + bin + r * (anh[q] + bhn)));
      float n = 1.f - 2.f / (e2 + 1.f);          // tanh
      float hn = (1.f - z) * n + z * h_q[q];
      bool valid = (t < len_q[q]);
      hn = valid ? hn : h_q[q];
      h_q[q] = hn;
      if (valid) out[rf_q[q] + (size_t)t * 512] = hn;   // fp32 store
      // pack (j,j^1) bf16 pair across lanes -> one 4B agent-release store
      unsigned int hb = f2b(hn);
      unsigned int ob = (unsigned int)__shfl_xor((int)hb, 1, 64) & 0xffffu;
      if ((jc & 1) == 0) {
        unsigned int pv = (hb & 0xffffu) | (ob << 16);
        __hip_atomic_store((unsigned int*)(hxout + hxo_q[q]), pv,
                           __ATOMIC_RELEASE, __HIP_MEMORY_SCOPE_AGENT);
      }
    }
    // ---- commit tok prefetch (fp32 -> bf16) to LDS for step t+1 ----
#pragma unroll
    for (int c = 0; c < 5; ++c) {
      FRAG u;
      u.s[0] = f2b(tr[c].x); u.s[1] = f2b(tr[c].y);
      u.s[2] = f2b(tr[c].z); u.s[3] = f2b(tr[c].w);
      *(uint2*)(&tokb[nbuf][trow[c] * 328 + tcu[c] * 4]) = u.u2[0];
    }
    __threadfence();
    __syncthreads();
    if (tid == 0) {
      __hip_atomic_fetch_add(ctr + g, 1ull, __ATOMIC_RELEASE, __HIP_MEMORY_SCOPE_AGENT);
      unsigned long long tgt = 8ull * (unsigned long long)(t + 1);
      long guard = 0;
      while (__hip_atomic_load(ctr + g, __ATOMIC_ACQUIRE, __HIP_MEMORY_SCOPE_AGENT) < tgt) {
        __builtin_amdgcn_s_sleep(2);
        if (++guard > 2000000L) break;   // bail out instead of hanging
      }
    }
    __syncthreads();
  }
#pragma unroll
  for (int q = 0; q < 4; ++q) out[hid_q[q]] = h_q[q];
}

// =====================================================================
// out_embs pack (300 fp32/row) + out_msks + rfts tail zeros.
// =====================================================================
__global__ __launch_bounds__(256, 4) void pack_embs(
    const int* __restrict__ inds, const int* __restrict__ lens,
    const float* __restrict__ emb, float* __restrict__ out)
{
  const int b = blockIdx.y;
  const int p = blockIdx.x * 4 + (threadIdx.x >> 6);
  const int l = threadIdx.x & 63;
  const int l0 = lens[b * 3], l1 = lens[b * 3 + 1], l2 = lens[b * 3 + 2];
  const int tlen = l0 + l1 + l2;
  if (l == 0)
    out[OUT_MSKS + (size_t)b * 768 + p] = (p < tlen) ? 1.0f : 0.0f;
  const size_t rfoff = OUT_RFTS + ((size_t)b * 768 + p) * 512;
  const size_t eboff = OUT_EMBS + ((size_t)b * 768 + p) * 300;
  if (p >= tlen) {
    const float4 z4 = make_float4(0.f, 0.f, 0.f, 0.f);
    *(float4*)(out + rfoff + (size_t)l * 8)     = z4;          // 512 = 64*8
    *(float4*)(out + rfoff + (size_t)l * 8 + 4) = z4;
    for (int u = l; u < 75; u += 64)                           // 300 = 75*4
      *(float4*)(out + eboff + (size_t)u * 4) = z4;
  } else {
    int s, tt;
    if (p < l0)           { s = 0; tt = p; }
    else if (p < l0 + l1) { s = 1; tt = p - l0; }
    else                  { s = 2; tt = p - l0 - l1; }
    const int ind = inds[(b * 3 + s) * 256 + tt];
    const float* src = emb + (size_t)ind * 300;
    for (int u = l; u < 75; u += 64)
      *(float4*)(out + eboff + (size_t)u * 4) = *(const float4*)(src + (size_t)u * 4);
  }
}

// =====================================================================
// GCN.  h1 = relu(adj @ (x@gw1) + gb1); out = adj @ (h1@gw2) + gb2
// =====================================================================
__global__ __launch_bounds__(256, 2) void gcn1(
    const float* __restrict__ sgx, const float* __restrict__ adj,
    const float* __restrict__ gw1, const float* __restrict__ gb1,
    float* __restrict__ h1)
{
  const int cb = blockIdx.x, b = blockIdx.y;
  const int tid = threadIdx.x;
  __shared__ float xs[18 * 600];
  __shared__ float adjs[324];
  __shared__ float ts[1152];
  for (int i = tid; i < 18 * 600; i += 256) xs[i] = sgx[(size_t)b * 10800 + i];
  for (int i = tid; i < 324; i += 256) adjs[i] = adj[(size_t)b * 324 + i];
  __syncthreads();
  const int c0 = cb * 64;
  for (int o = tid; o < 1152; o += 256) {
    const int r = o >> 6, c = c0 + (o & 63);
    float a0 = 0.f, a1 = 0.f;
    if (c < 600) {
      const float* xr = xs + r * 600;
      for (int k = 0; k < 600; k += 2) {
        a0 += xr[k]     * gw1[(size_t)k * 600 + c];
        a1 += xr[k + 1] * gw1[(size_t)(k + 1) * 600 + c];
      }
    }
    ts[o] = a0 + a1;
  }
  __syncthreads();
  for (int o = tid; o < 1152; o += 256) {
    const int n = o >> 6, cl = o & 63, c = c0 + cl;
    if (c >= 600) continue;
    float acc = gb1[c];
#pragma unroll
    for (int m = 0; m < 18; ++m) acc += adjs[n * 18 + m] * ts[m * 64 + cl];
    h1[(size_t)b * 10800 + n * 600 + c] = fmaxf(acc, 0.f);
  }
}

__global__ __launch_bounds__(256, 2) void gcn2(
    const float* __restrict__ h1, const float* __restrict__ adj,
    const float* __restrict__ gw2, const float* __restrict__ gb2,
    float* __restrict__ out)
{
  const int cb = blockIdx.x, b = blockIdx.y;
  const int tid = threadIdx.x;
  __shared__ float xs[18 * 600];
  __shared__ float adjs[324];
  __shared__ float ts[1152];
  for (int i = tid; i < 18 * 600; i += 256) xs[i] = h1[(size_t)b * 10800 + i];
  for (int i = tid; i < 324; i += 256) adjs[i] = adj[(size_t)b * 324 + i];
  __syncthreads();
  const int c0 = cb * 64;
  for (int o = tid; o < 1152; o += 256) {
    const int r = o >> 6, c = c0 + (o & 63);
    const float* xr = xs + r * 600;
    float a0 = 0.f, a1 = 0.f;
    for (int k = 0; k < 600; k += 2) {
      a0 += xr[k]     * gw2[(size_t)k * 1024 + c];
      a1 += xr[k + 1] * gw2[(size_t)(k + 1) * 1024 + c];
    }
    ts[o] = a0 + a1;
  }
  __syncthreads();
  for (int o = tid; o < 1152; o += 256) {
    const int n = o >> 6, cl = o & 63, c = c0 + cl;
    float acc = gb2[c];
#pragma unroll
    for (int m = 0; m < 18; ++m) acc += adjs[n * 18 + m] * ts[m * 64 + cl];
    out[OUT_SG + (size_t)b * 18432 + n * 1024 + c] = acc;
  }
}

// =====================================================================
extern "C" void kernel_launch(void* const* d_in, const int* in_sizes, int n_in,
                              void* d_out, int out_size, void* d_ws, size_t ws_size,
                              hipStream_t stream)
{
  (void)in_sizes; (void)n_in; (void)out_size; (void)ws_size;
  const int*   inds = (const int*)d_in[0];
  const int*   lens = (const int*)d_in[1];
  const float* emb  = (const float*)d_in[2];
  const float* w_ih = (const float*)d_in[3];
  const float* w_hh = (const float*)d_in[4];
  const float* b_ih = (const float*)d_in[5];
  const float* b_hh = (const float*)d_in[6];
  const float* sgx  = (const float*)d_in[7];
  const float* adj  = (const float*)d_in[8];
  const float* gw1  = (const float*)d_in[9];
  const float* gb1  = (const float*)d_in[10];
  const float* gw2  = (const float*)d_in[11];
  const float* gb2  = (const float*)d_in[12];
  float* out = (float*)d_out;
  char* ws = (char*)d_ws;
  ushort_t* hx = (ushort_t*)(ws + WS_HX);
  unsigned long long* ctr = (unsigned long long*)(ws + WS_CTR);
  float* h1 = (float*)(ws + WS_H1);

  // zero h0 double-buffer + barrier counters (ws is poisoned 0xAA)
  hipMemsetAsync(ws, 0, 393216 + 256, stream);
  gru_fused<<<dim3(96),      256, 0, stream>>>(inds, lens, emb, w_ih, w_hh,
                                               b_ih, b_hh, hx, ctr, out);
  pack_embs<<<dim3(192, 64), 256, 0, stream>>>(inds, lens, emb, out);
  gcn1     <<<dim3(10, 64),  256, 0, stream>>>(sgx, adj, gw1, gb1, h1);
  gcn2     <<<dim3(16, 64),  256, 0, stream>>>(h1, adj, gw2, gb2, out);
}

// Round 5
// 2299.748 us; speedup vs baseline: 5.9288x; 5.9288x over previous
//
#include <hip/hip_runtime.h>

// ---------- problem constants ----------
// V=50000, E=300, H=512, BS=64, NSEG=3, SLEN=256 -> B3=192
// NNODE=18, NFEAT=600, NHID=600, NOUT=1024
// ALL float inputs/outputs are fp32 (reference is jnp.float32).

typedef unsigned short ushort_t;
typedef __attribute__((ext_vector_type(8))) short bf16x8;   // 8 bf16 = 4 VGPRs
typedef __attribute__((ext_vector_type(4))) float f32x4;

// output element offsets (fp32 elements)
#define OUT_RFTS 0UL
#define OUT_EMBS 25165824UL          // 64*768*512
#define OUT_MSKS 39911424UL          // + 64*768*300
#define OUT_SG   39960576UL          // + 64*768
#define OUT_HIDS 41140224UL          // + 64*18*1024   (end 41238528 = out_size)

// workspace byte offsets
#define WS_HX   0UL                  // hx: 2*192*512 bf16 = 393,216 B (internal)
#define WS_FLG  393216UL             // flags: 96 x 128B lines = 12,288 B
#define WS_H1   405504UL             // h1: 64*18*600 fp32 = 2,764,800 B

__device__ __forceinline__ ushort_t f2b(float f) {
  unsigned int u = __float_as_uint(f);
  u += 0x7fffu + ((u >> 16) & 1u);          // RNE
  return (ushort_t)(u >> 16);
}

union FRAG { ushort_t s[8]; bf16x8 v; uint2 u2[2]; };

// build a bf16x8 fragment from 8 fp32 (16B-aligned), with per-half validity
__device__ __forceinline__ bf16x8 frag_from_f32(const float* p, bool v0, bool v1) {
  float4 a = v0 ? *(const float4*)p       : make_float4(0.f, 0.f, 0.f, 0.f);
  float4 b = v1 ? *(const float4*)(p + 4) : make_float4(0.f, 0.f, 0.f, 0.f);
  FRAG u;
  u.s[0] = f2b(a.x); u.s[1] = f2b(a.y); u.s[2] = f2b(a.z); u.s[3] = f2b(a.w);
  u.s[4] = f2b(b.x); u.s[5] = f2b(b.y); u.s[6] = f2b(b.z); u.s[7] = f2b(b.w);
  return u.v;
}

// =====================================================================
// Fused GRU: 12 groups (16 samples) x 8 gate-slices = 96 WGs, 1 WG/CU.
// Weights register/AGPR-resident as bf16 frags. Per-step h exchange:
//   relaxed agent stores of h  ->  __syncthreads (vmcnt drain)
//   -> tid0 release-stores flag[g,p]=t+1 (own 128B line)
//   next step: lanes 0..7 acquire-poll the 8 flags, then relaxed loads.
// No RMW atomics, no threadfence, no shared hot cacheline.
// =====================================================================
__global__ __launch_bounds__(256, 1) void gru_fused(
    const int* __restrict__ inds, const int* __restrict__ lens,
    const float* __restrict__ emb, const float* __restrict__ w_ih,
    const float* __restrict__ w_hh, const float* __restrict__ b_ih,
    const float* __restrict__ b_hh, ushort_t* __restrict__ hx,
    unsigned int* __restrict__ flags, float* __restrict__ out)
{
  const int g = blockIdx.x >> 3;        // group 0..11
  const int p = blockIdx.x & 7;         // gate-slice 0..7 (64 j each)
  const int tid = threadIdx.x;
  const int w = tid >> 6;               // wave 0..3, owns j-subtile w
  const int l = tid & 63;
  const int jc = l & 15;
  const int quad = l >> 4;
  const int jg = p * 64 + w * 16 + jc;  // j in [0,512)

  __shared__ ushort_t hst[16 * 520];    // staged h (16 x 512 bf16, stride 520)
  __shared__ ushort_t tokb[2][16 * 328];// staged tok (16 x 320 bf16, stride 328)
  __shared__ int sidx[16];              // emb row indices for next step

  // ---- register-resident w_hh slice: B[n=l&15][k=quad*8+i] frags ----
  bf16x8 bwh[3][16];
#pragma unroll
  for (int g3 = 0; g3 < 3; ++g3) {
    const float* wr = w_hh + (size_t)(g3 * 512 + jg) * 512 + quad * 8;
#pragma unroll
    for (int kc = 0; kc < 16; ++kc)
      bwh[g3][kc] = frag_from_f32(wr + kc * 32, true, true);
  }
  // ---- register-resident w_ih slice (K=300 padded to 320 with zeros) ----
  bf16x8 bwx[3][10];
#pragma unroll
  for (int g3 = 0; g3 < 3; ++g3) {
    const float* wr = w_ih + (size_t)(g3 * 512 + jg) * 300;
#pragma unroll
    for (int kc = 0; kc < 10; ++kc) {
      const int k0 = kc * 32 + quad * 8;
      bwx[g3][kc] = frag_from_f32(wr + k0, k0 + 3 < 300, k0 + 7 < 300);
    }
  }
  const float bsr = b_ih[jg] + b_hh[jg];
  const float bsz = b_ih[512 + jg] + b_hh[512 + jg];
  const float bin = b_ih[1024 + jg];
  const float bhn = b_hh[1024 + jg];

  int Tg = 0;
  for (int i = 0; i < 16; ++i) Tg = max(Tg, lens[g * 16 + i]);

  int len_q[4]; size_t rf_q[4], hxo_q[4], hid_q[4];
  float h_q[4] = {0.f, 0.f, 0.f, 0.f};
#pragma unroll
  for (int q = 0; q < 4; ++q) {
    int sl = quad * 4 + q;              // sample-in-group (D-row layout)
    int b3 = g * 16 + sl;
    len_q[q] = lens[b3];
    int b = b3 / 3, seg = b3 - b * 3;
    int off = 0;
    for (int ss = 0; ss < seg; ++ss) off += lens[b * 3 + ss];
    rf_q[q]  = OUT_RFTS + ((size_t)b * 768 + off) * 512 + jg;
    hxo_q[q] = (size_t)b3 * 512 + (size_t)(jg & ~1);
    hid_q[q] = OUT_HIDS + (size_t)b3 * 512 + jg;
  }

  // per-thread constant mapping for tok staging: 1280 slots = 16 rows x 80 f4
  int trow[5], tcu[5];
#pragma unroll
  for (int c = 0; c < 5; ++c) {
    int u = c * 256 + tid;
    trow[c] = u / 80;
    tcu[c]  = u - trow[c] * 80;
  }

  // ---- prologue: stage tok for t=0 into tokb[0] ----
  if (tid < 16) sidx[tid] = inds[(size_t)(g * 16 + tid) * 256 + 0];
  __syncthreads();
#pragma unroll
  for (int c = 0; c < 5; ++c) {
    float4 v = make_float4(0.f, 0.f, 0.f, 0.f);
    if (tcu[c] < 75)
      v = *(const float4*)(emb + (size_t)sidx[trow[c]] * 300 + tcu[c] * 4);
    FRAG u; u.s[0] = f2b(v.x); u.s[1] = f2b(v.y); u.s[2] = f2b(v.z); u.s[3] = f2b(v.w);
    *(uint2*)(&tokb[0][trow[c] * 328 + tcu[c] * 4]) = u.u2[0];
  }
  __syncthreads();

  const int HXE = 192 * 512;            // bf16 elements per hx buffer
  const f32x4 z4 = {0.f, 0.f, 0.f, 0.f};

  for (int t = 0; t < Tg; ++t) {
    const int buf = t & 1, nbuf = buf ^ 1;
    // ---- wait for all 8 slices of this group to have published h_t ----
    if (tid < 8) {
      long guard = 0;
      while (__hip_atomic_load(&flags[(g * 8 + tid) * 32],
                               __ATOMIC_ACQUIRE, __HIP_MEMORY_SCOPE_AGENT)
             < (unsigned int)t) {
        __builtin_amdgcn_s_sleep(1);
        if (++guard > 20000000L) break;   // bail out instead of hanging
      }
    }
    if (tid < 16) {
      int tt = (t + 1 < 256) ? t + 1 : 255;
      sidx[tid] = inds[(size_t)(g * 16 + tid) * 256 + tt];
    }
    __syncthreads();
    // ---- stage h (relaxed agent loads; ordering via acquire-polls) ----
    {
      const unsigned long long* src =
          (const unsigned long long*)(hx + (size_t)buf * HXE + (size_t)g * 16 * 512);
#pragma unroll
      for (int c = 0; c < 8; ++c) {
        int idx = c * 256 + tid;        // 0..2047 (8B units), 128/row
        unsigned long long v = __hip_atomic_load(
            (unsigned long long*)(src + idx), __ATOMIC_RELAXED, __HIP_MEMORY_SCOPE_AGENT);
        int row = idx >> 7, col = idx & 127;
        *(unsigned long long*)(&hst[row * 520 + col * 4]) = v;
      }
    }
    __syncthreads();
    // ---- prefetch tok for t+1 (fp32; converted at commit time) ----
    float4 tr[5];
#pragma unroll
    for (int c = 0; c < 5; ++c) {
      tr[c] = make_float4(0.f, 0.f, 0.f, 0.f);
      if (tcu[c] < 75)
        tr[c] = *(const float4*)(emb + (size_t)sidx[trow[c]] * 300 + tcu[c] * 4);
    }
    // ---- MFMA phase: gates = h @ w_hh^T + x @ w_ih^T ----
    f32x4 accr = z4, accz = z4, anh = z4, anx = z4;
#pragma unroll
    for (int kc = 0; kc < 16; ++kc) {
      bf16x8 af = *(const bf16x8*)(&hst[(l & 15) * 520 + kc * 32 + quad * 8]);
      accr = __builtin_amdgcn_mfma_f32_16x16x32_bf16(af, bwh[0][kc], accr, 0, 0, 0);
      accz = __builtin_amdgcn_mfma_f32_16x16x32_bf16(af, bwh[1][kc], accz, 0, 0, 0);
      anh  = __builtin_amdgcn_mfma_f32_16x16x32_bf16(af, bwh[2][kc], anh, 0, 0, 0);
    }
#pragma unroll
    for (int kc = 0; kc < 10; ++kc) {
      bf16x8 xf = *(const bf16x8*)(&tokb[buf][(l & 15) * 328 + kc * 32 + quad * 8]);
      accr = __builtin_amdgcn_mfma_f32_16x16x32_bf16(xf, bwx[0][kc], accr, 0, 0, 0);
      accz = __builtin_amdgcn_mfma_f32_16x16x32_bf16(xf, bwx[1][kc], accz, 0, 0, 0);
      anx  = __builtin_amdgcn_mfma_f32_16x16x32_bf16(xf, bwx[2][kc], anx, 0, 0, 0);
    }
    // ---- gate math + stores ----
    ushort_t* hxout = hx + (size_t)nbuf * HXE;
#pragma unroll
    for (int q = 0; q < 4; ++q) {
      float pr = accr[q] + bsr;
      float pz = accz[q] + bsz;
      float r = 1.f / (1.f + __expf(-pr));
      float z = 1.f / (1.f + __expf(-pz));
      float e2 = __expf(2.f * (anx[q] + bin + r * (anh[q] + bhn)));
      float n = 1.f - 2.f / (e2 + 1.f);          // tanh
      float hn = (1.f - z) * n + z * h_q[q];
      bool valid = (t < len_q[q]);
      hn = valid ? hn : h_q[q];
      h_q[q] = hn;
      if (valid) out[rf_q[q] + (size_t)t * 512] = hn;   // fp32 store
      // pack (j,j^1) bf16 pair across lanes -> one 4B relaxed agent store
      unsigned int hb = f2b(hn);
      unsigned int ob = (unsigned int)__shfl_xor((int)hb, 1, 64) & 0xffffu;
      if ((jc & 1) == 0) {
        unsigned int pv = (hb & 0xffffu) | (ob << 16);
        __hip_atomic_store((unsigned int*)(hxout + hxo_q[q]), pv,
                           __ATOMIC_RELAXED, __HIP_MEMORY_SCOPE_AGENT);
      }
    }
    // ---- commit tok prefetch (fp32 -> bf16) to LDS for step t+1 ----
#pragma unroll
    for (int c = 0; c < 5; ++c) {
      FRAG u;
      u.s[0] = f2b(tr[c].x); u.s[1] = f2b(tr[c].y);
      u.s[2] = f2b(tr[c].z); u.s[3] = f2b(tr[c].w);
      *(uint2*)(&tokb[nbuf][trow[c] * 328 + tcu[c] * 4]) = u.u2[0];
    }
    __syncthreads();   // compiler drains vmcnt before s_barrier -> h stores done
    if (tid == 0)
      __hip_atomic_store(&flags[(g * 8 + p) * 32], (unsigned int)(t + 1),
                         __ATOMIC_RELEASE, __HIP_MEMORY_SCOPE_AGENT);
  }
#pragma unroll
  for (int q = 0; q < 4; ++q) out[hid_q[q]] = h_q[q];
}

// =====================================================================
// out_embs pack (300 fp32/row) + out_msks + rfts tail zeros.
// =====================================================================
__global__ __launch_bounds__(256, 4) void pack_embs(
    const int* __restrict__ inds, const int* __restrict__ lens,
    const float* __restrict__ emb, float* __restrict__ out)
{
  const int b = blockIdx.y;
  const int p = blockIdx.x * 4 + (threadIdx.x >> 6);
  const int l = threadIdx.x & 63;
  const int l0 = lens[b * 3], l1 = lens[b * 3 + 1], l2 = lens[b * 3 + 2];
  const int tlen = l0 + l1 + l2;
  if (l == 0)
    out[OUT_MSKS + (size_t)b * 768 + p] = (p < tlen) ? 1.0f : 0.0f;
  const size_t rfoff = OUT_RFTS + ((size_t)b * 768 + p) * 512;
  const size_t eboff = OUT_EMBS + ((size_t)b * 768 + p) * 300;
  if (p >= tlen) {
    const float4 z4 = make_float4(0.f, 0.f, 0.f, 0.f);
    *(float4*)(out + rfoff + (size_t)l * 8)     = z4;          // 512 = 64*8
    *(float4*)(out + rfoff + (size_t)l * 8 + 4) = z4;
    for (int u = l; u < 75; u += 64)                           // 300 = 75*4
      *(float4*)(out + eboff + (size_t)u * 4) = z4;
  } else {
    int s, tt;
    if (p < l0)           { s = 0; tt = p; }
    else if (p < l0 + l1) { s = 1; tt = p - l0; }
    else                  { s = 2; tt = p - l0 - l1; }
    const int ind = inds[(b * 3 + s) * 256 + tt];
    const float* src = emb + (size_t)ind * 300;
    for (int u = l; u < 75; u += 64)
      *(float4*)(out + eboff + (size_t)u * 4) = *(const float4*)(src + (size_t)u * 4);
  }
}

// =====================================================================
// GCN.  h1 = relu(adj @ (x@gw1) + gb1); out = adj @ (h1@gw2) + gb2
// =====================================================================
__global__ __launch_bounds__(256, 2) void gcn1(
    const float* __restrict__ sgx, const float* __restrict__ adj,
    const float* __restrict__ gw1, const float* __restrict__ gb1,
    float* __restrict__ h1)
{
  const int cb = blockIdx.x, b = blockIdx.y;
  const int tid = threadIdx.x;
  __shared__ float xs[18 * 600];
  __shared__ float adjs[324];
  __shared__ float ts[1152];
  for (int i = tid; i < 18 * 600; i += 256) xs[i] = sgx[(size_t)b * 10800 + i];
  for (int i = tid; i < 324; i += 256) adjs[i] = adj[(size_t)b * 324 + i];
  __syncthreads();
  const int c0 = cb * 64;
  for (int o = tid; o < 1152; o += 256) {
    const int r = o >> 6, c = c0 + (o & 63);
    float a0 = 0.f, a1 = 0.f;
    if (c < 600) {
      const float* xr = xs + r * 600;
      for (int k = 0; k < 600; k += 2) {
        a0 += xr[k]     * gw1[(size_t)k * 600 + c];
        a1 += xr[k + 1] * gw1[(size_t)(k + 1) * 600 + c];
      }
    }
    ts[o] = a0 + a1;
  }
  __syncthreads();
  for (int o = tid; o < 1152; o += 256) {
    const int n = o >> 6, cl = o & 63, c = c0 + cl;
    if (c >= 600) continue;
    float acc = gb1[c];
#pragma unroll
    for (int m = 0; m < 18; ++m) acc += adjs[n * 18 + m] * ts[m * 64 + cl];
    h1[(size_t)b * 10800 + n * 600 + c] = fmaxf(acc, 0.f);
  }
}

__global__ __launch_bounds__(256, 2) void gcn2(
    const float* __restrict__ h1, const float* __restrict__ adj,
    const float* __restrict__ gw2, const float* __restrict__ gb2,
    float* __restrict__ out)
{
  const int cb = blockIdx.x, b = blockIdx.y;
  const int tid = threadIdx.x;
  __shared__ float xs[18 * 600];
  __shared__ float adjs[324];
  __shared__ float ts[1152];
  for (int i = tid; i < 18 * 600; i += 256) xs[i] = h1[(size_t)b * 10800 + i];
  for (int i = tid; i < 324; i += 256) adjs[i] = adj[(size_t)b * 324 + i];
  __syncthreads();
  const int c0 = cb * 64;
  for (int o = tid; o < 1152; o += 256) {
    const int r = o >> 6, c = c0 + (o & 63);
    const float* xr = xs + r * 600;
    float a0 = 0.f, a1 = 0.f;
    for (int k = 0; k < 600; k += 2) {
      a0 += xr[k]     * gw2[(size_t)k * 1024 + c];
      a1 += xr[k + 1] * gw2[(size_t)(k + 1) * 1024 + c];
    }
    ts[o] = a0 + a1;
  }
  __syncthreads();
  for (int o = tid; o < 1152; o += 256) {
    const int n = o >> 6, cl = o & 63, c = c0 + cl;
    float acc = gb2[c];
#pragma unroll
    for (int m = 0; m < 18; ++m) acc += adjs[n * 18 + m] * ts[m * 64 + cl];
    out[OUT_SG + (size_t)b * 18432 + n * 1024 + c] = acc;
  }
}

// =====================================================================
extern "C" void kernel_launch(void* const* d_in, const int* in_sizes, int n_in,
                              void* d_out, int out_size, void* d_ws, size_t ws_size,
                              hipStream_t stream)
{
  (void)in_sizes; (void)n_in; (void)out_size; (void)ws_size;
  const int*   inds = (const int*)d_in[0];
  const int*   lens = (const int*)d_in[1];
  const float* emb  = (const float*)d_in[2];
  const float* w_ih = (const float*)d_in[3];
  const float* w_hh = (const float*)d_in[4];
  const float* b_ih = (const float*)d_in[5];
  const float* b_hh = (const float*)d_in[6];
  const float* sgx  = (const float*)d_in[7];
  const float* adj  = (const float*)d_in[8];
  const float* gw1  = (const float*)d_in[9];
  const float* gb1  = (const float*)d_in[10];
  const float* gw2  = (const float*)d_in[11];
  const float* gb2  = (const float*)d_in[12];
  float* out = (float*)d_out;
  char* ws = (char*)d_ws;
  ushort_t* hx = (ushort_t*)(ws + WS_HX);
  unsigned int* flags = (unsigned int*)(ws + WS_FLG);
  float* h1 = (float*)(ws + WS_H1);

  // zero h0 double-buffer + flags (ws is poisoned 0xAA)
  hipMemsetAsync(ws, 0, 405504, stream);
  gru_fused<<<dim3(96),      256, 0, stream>>>(inds, lens, emb, w_ih, w_hh,
                                               b_ih, b_hh, hx, flags, out);
  pack_embs<<<dim3(192, 64), 256, 0, stream>>>(inds, lens, emb, out);
  gcn1     <<<dim3(10, 64),  256, 0, stream>>>(sgx, adj, gw1, gb1, h1);
  gcn2     <<<dim3(16, 64),  256, 0, stream>>>(h1, adj, gw2, gb2, out);
}